// Round 15
// baseline (45.402 us; speedup 1.0000x reference)
//
#include <hip/hip_runtime.h>
#include <math.h>

#define N_TOK 4096
#define BS 2
#define NHEAD 8
#define ROW 256                     // floats per token row (8 heads * 32)
#define NE 194560                   // edges per batch
#define PT_OFF 64                   // front pad (floats) for e0<0 reads
#define PT_SZ (NE * NHEAD + 1024)   // per-batch pT floats incl front/back pad
#define NSS 35                      // supersteps; u = 2s+half in [0,70)

// deg(i) = 32 + (i%32); rowptr(i) = 32i + 496*(i>>5) + r(r-1)/2
__device__ __forceinline__ int rowptr_a(int i) {
    const int r = i & 31;
    return 32 * i + 496 * (i >> 5) + ((r * (r - 1)) >> 1);
}

#if __has_builtin(__builtin_amdgcn_exp2f)
#define EXP2F(x) __builtin_amdgcn_exp2f(x)
#else
#define EXP2F(x) exp2f(x)
#endif

// Quad-perm DPP butterflies: VALU-pipe cross-lane within groups of 4.
#if __has_builtin(__builtin_amdgcn_mov_dpp)
__device__ __forceinline__ float dpp_xor1(float x) {
    return __int_as_float(__builtin_amdgcn_mov_dpp(__float_as_int(x), 0xB1, 0xF, 0xF, true));
}
__device__ __forceinline__ float dpp_xor2(float x) {
    return __int_as_float(__builtin_amdgcn_mov_dpp(__float_as_int(x), 0x4E, 0xF, 0xF, true));
}
#else
__device__ __forceinline__ float dpp_xor1(float x) { return __shfl_xor(x, 1, 4); }
__device__ __forceinline__ float dpp_xor2(float x) { return __shfl_xor(x, 2, 4); }
#endif

// 1024 blocks; wgid&7 ~ physical XCD: each XCD owns one batch and a contiguous
// 128-wide m-range (token window ~1.5K -> ~3MB < 4MB per-XCD L2).
// Jobs of 8 tokens {8m+7c}: 7c mod 8 bijective -> all tokens covered once.
__device__ __forceinline__ void map_block(int wg, int& b, int& m) {
    const int xcd = wg & 7;
    b = xcd & 1;
    m = ((xcd >> 1) << 7) + (wg >> 3);   // region*128 + slot, m in [0,512)
}

// ---------------------------------------------------------------------------
// fwd: one block = 2 waves = job of 8 dsts {8m+7c}. Lane layout (R14): half
// picks row u=2s+half; 4 lanes per head, 8 floats/lane. Each row load feeds
// 8 accumulators -> half the L1 traffic per FLOP vs 4-dst jobs. L1 reduce =
// in-lane tree + 2 DPP quad-swaps (no LDS pipe in the chain). Depth-2
// register pipeline. p staged in LDS (16KB, reused for merge after flush).
// ---------------------------------------------------------------------------
__global__ __launch_bounds__(128, 2)
void fwd_kernel(const float* __restrict__ vf, const float* __restrict__ q,
                const float* __restrict__ k, float* __restrict__ pT,
                float* __restrict__ vo) {
    int b, m; map_block(blockIdx.x, b, m);
    const int wid  = threadIdx.x >> 6;
    const int lane = threadIdx.x & 63;
    const int half = lane >> 5;
    const int hl   = lane & 31;
    const int h    = hl >> 2;
    const int quad = hl & 3;
    const int segf = hl * 8;           // float offset of lane's 8-float segment

    const size_t bstr = (size_t)N_TOK * ROW;
    const float* qb  = q  + b * bstr;
    const float* kb  = k  + b * bstr;
    const float* vfb = vf + b * bstr;

    const int d0 = 8 * m;
    int deg[8];
    float4 qva[8], qvb[8];
    #pragma unroll
    for (int c = 0; c < 8; ++c) {
        const int dstc = (d0 + 7 * c) & (N_TOK - 1);
        deg[c] = 32 + (dstc & 31);
        const float* qr = qb + (size_t)dstc * ROW + segf;
        qva[c] = *(const float4*)qr;
        qvb[c] = *(const float4*)(qr + 4);
    }

    // phase A: s_p[c][j][h] = c*512 + j*8 + h (4096 floats)
    // phase B: merge[w][c][256] = (w*8+c)*256 (4096 floats)
    __shared__ float s_buf[8 * 64 * NHEAD];
    __shared__ float s_s[2][8][NHEAD];
    __shared__ float s_inv[8][NHEAD];

    const float s2 = -0.25503494f;          // -1/sqrt(32) * log2(e)
    float4 acc0[8], acc1[8];
    float  ssum[8];
    #pragma unroll
    for (int c = 0; c < 8; ++c) {
        acc0[c] = make_float4(0.f,0.f,0.f,0.f);
        acc1[c] = make_float4(0.f,0.f,0.f,0.f);
        ssum[c] = 0.f;
    }

    const int dsel0 = 32 + (((d0 + 7 * quad) & (N_TOK - 1)) & 31);
    const int dsel1 = 32 + (((d0 + 7 * (quad + 4)) & (N_TOK - 1)) & 31);

    int s = wid;
    const int u0 = 2 * s + half;
    const int r0 = (d0 + 1 + 7 * u0) & (N_TOK - 1);
    float4 ka0 = *(const float4*)(kb  + (size_t)r0 * ROW + segf);
    float4 ka1 = *(const float4*)(kb  + (size_t)r0 * ROW + segf + 4);
    float4 fa0 = *(const float4*)(vfb + (size_t)r0 * ROW + segf);
    float4 fa1 = *(const float4*)(vfb + (size_t)r0 * ROW + segf + 4);

    for (; s < NSS; s += 2) {
        // prefetch superstep s+2 (wrapped row: always legal; OOB masked)
        const int un = 2 * (s + 2) + half;
        const int rn = (d0 + 1 + 7 * un) & (N_TOK - 1);
        const float4 kn0 = *(const float4*)(kb  + (size_t)rn * ROW + segf);
        const float4 kn1 = *(const float4*)(kb  + (size_t)rn * ROW + segf + 4);
        const float4 fn0 = *(const float4*)(vfb + (size_t)rn * ROW + segf);
        const float4 fn1 = *(const float4*)(vfb + (size_t)rn * ROW + segf + 4);

        const int ubase = 2 * s;            // u = ubase + half (per-lane)
        float p_sel0 = 0.f, p_sel1 = 0.f;
        #pragma unroll
        for (int c = 0; c < 8; ++c) {
            float t0 = fabsf(qva[c].x - ka0.x) + fabsf(qva[c].y - ka0.y)
                     + fabsf(qva[c].z - ka0.z) + fabsf(qva[c].w - ka0.w);
            float t1 = fabsf(qvb[c].x - ka1.x) + fabsf(qvb[c].y - ka1.y)
                     + fabsf(qvb[c].z - ka1.z) + fabsf(qvb[c].w - ka1.w);
            float d8 = t0 + t1;             // 8-float partial in-lane
            d8 += dpp_xor1(d8);             // quad butterfly: VALU-pipe only
            d8 += dpp_xor2(d8);             // all 4 lanes hold full 32-elem L1
            const int j = ubase + half - c;
            const float pe = EXP2F(d8 * s2);
            const float p  = ((unsigned)j < (unsigned)deg[c]) ? pe : 0.f;
            ssum[c] += p;
            acc0[c].x += p * fa0.x; acc0[c].y += p * fa0.y;
            acc0[c].z += p * fa0.z; acc0[c].w += p * fa0.w;
            acc1[c].x += p * fa1.x; acc1[c].y += p * fa1.y;
            acc1[c].z += p * fa1.z; acc1[c].w += p * fa1.w;
            if (c == quad)     p_sel0 = p;
            if (c == quad + 4) p_sel1 = p;
        }
        const int j0 = ubase + half - quad;
        if ((unsigned)j0 < (unsigned)dsel0)
            s_buf[quad * 512 + j0 * NHEAD + h] = p_sel0;
        const int j1 = ubase + half - quad - 4;
        if ((unsigned)j1 < (unsigned)dsel1)
            s_buf[(quad + 4) * 512 + j1 * NHEAD + h] = p_sel1;

        ka0 = kn0; ka1 = kn1; fa0 = fn0; fa1 = fn1;
    }

    // half-merge in registers (one-time cross-lane xor32)
    #pragma unroll
    for (int c = 0; c < 8; ++c) {
        acc0[c].x += __shfl_xor(acc0[c].x, 32); acc0[c].y += __shfl_xor(acc0[c].y, 32);
        acc0[c].z += __shfl_xor(acc0[c].z, 32); acc0[c].w += __shfl_xor(acc0[c].w, 32);
        acc1[c].x += __shfl_xor(acc1[c].x, 32); acc1[c].y += __shfl_xor(acc1[c].y, 32);
        acc1[c].z += __shfl_xor(acc1[c].z, 32); acc1[c].w += __shfl_xor(acc1[c].w, 32);
        ssum[c]   += __shfl_xor(ssum[c], 32);
    }

    if (half == 0 && quad == 0) {
        #pragma unroll
        for (int c = 0; c < 8; ++c) s_s[wid][c][h] = ssum[c];
    }
    __syncthreads();
    if (threadIdx.x < 64) {
        const int cc = threadIdx.x >> 3, hh = threadIdx.x & 7;
        s_inv[cc][hh] = 1.f / (s_s[0][cc][hh] + s_s[1][cc][hh]);
    }
    __syncthreads();

    // pT flush: normalized weights, edge-major [e][h], fully coalesced runs.
    float* pTb = pT + (size_t)b * PT_SZ + PT_OFF;
    #pragma unroll
    for (int c = 0; c < 8; ++c) {
        const int dstc  = (d0 + 7 * c) & (N_TOK - 1);
        const int basec = rowptr_a(dstc);
        const int n     = (32 + (dstc & 31)) * NHEAD;
        float* dstp = pTb + (size_t)basec * NHEAD;
        const float* srcp = &s_buf[c * 512];
        for (int idx = threadIdx.x; idx < n; idx += 128)
            dstp[idx] = srcp[idx] * s_inv[c][idx & 7];
    }
    __syncthreads();   // s_p consumed; reuse s_buf as merge[w][c][256]

    if (half == 0) {
        #pragma unroll
        for (int c = 0; c < 8; ++c) {
            *(float4*)(&s_buf[(wid * 8 + c) * 256 + segf])     = acc0[c];
            *(float4*)(&s_buf[(wid * 8 + c) * 256 + segf + 4]) = acc1[c];
        }
    }
    __syncthreads();

    // vo rows: wave w finalizes c = 4w..4w+3 (exclusive owner -> plain store)
    float* vob = vo + b * bstr;
    #pragma unroll
    for (int q2 = 0; q2 < 4; ++q2) {
        const int c = 4 * wid + q2;
        const int dstc = (d0 + 7 * c) & (N_TOK - 1);
        const float inv = s_inv[c][lane >> 3];
        const float4 a0 = *(const float4*)(&s_buf[(c)     * 256 + lane * 4]);
        const float4 a1 = *(const float4*)(&s_buf[(8 + c) * 256 + lane * 4]);
        float4 o;
        o.x = (a0.x + a1.x) * inv;
        o.y = (a0.y + a1.y) * inv;
        o.z = (a0.z + a1.z) * inv;
        o.w = (a0.w + a1.w) * inv;
        *(float4*)(vob + (size_t)dstc * ROW + lane * 4) = o;
    }
}

// ---------------------------------------------------------------------------
// rev: one block = 2 waves = job of 8 srcs {8m+7c}. Row d = 8m-1-7v per half
// (v = 2s+half-7); the 8 srcs' edges are e0..e0+7 (e0 = rowptr(d)+v). Each
// lane loads its own 8 weights pT[(e0+c)*8+h] (no shuffles in the loop);
// each vb row feeds 8 accumulators. Depth-2 register pipeline.
// ---------------------------------------------------------------------------
__global__ __launch_bounds__(128, 2)
void rev_kernel(const float* __restrict__ vb, const float* __restrict__ pT,
                float* __restrict__ vo) {
    int b, m; map_block(blockIdx.x, b, m);
    const int wid  = threadIdx.x >> 6;
    const int lane = threadIdx.x & 63;
    const int half = lane >> 5;
    const int hl   = lane & 31;
    const int h    = hl >> 2;
    const int segf = hl * 8;

    const size_t bstr = (size_t)N_TOK * ROW;
    const float* vbb = vb + b * bstr;
    const float* pTb = pT + (size_t)b * PT_SZ + PT_OFF;

    const int s0 = 8 * m;
    float4 acc0[8], acc1[8];
    #pragma unroll
    for (int c = 0; c < 8; ++c) {
        acc0[c] = make_float4(0.f,0.f,0.f,0.f);
        acc1[c] = make_float4(0.f,0.f,0.f,0.f);
    }

    int s = wid;
    int vA = 2 * s + half - 7;
    int dA = (s0 - 1 - 7 * vA) & (N_TOK - 1);
    float4 ba0 = *(const float4*)(vbb + (size_t)dA * ROW + segf);
    float4 ba1 = *(const float4*)(vbb + (size_t)dA * ROW + segf + 4);
    float pw[8];
    {
        const int e0 = rowptr_a(dA) + vA;
        #pragma unroll
        for (int c = 0; c < 8; ++c) pw[c] = pTb[(e0 + c) * NHEAD + h];
    }

    for (; s < NSS; s += 2) {
        // prefetch superstep s+2 (v+4); pads absorb edge-index overshoot
        const int vN = vA + 4;
        const int dN = (s0 - 1 - 7 * vN) & (N_TOK - 1);
        const float4 bn0 = *(const float4*)(vbb + (size_t)dN * ROW + segf);
        const float4 bn1 = *(const float4*)(vbb + (size_t)dN * ROW + segf + 4);
        float pn[8];
        {
            const int e0n = rowptr_a(dN) + vN;
            #pragma unroll
            for (int c = 0; c < 8; ++c) pn[c] = pTb[(e0n + c) * NHEAD + h];
        }

        const int degd = 32 + (dA & 31);    // per-lane (half-dependent)
        #pragma unroll
        for (int c = 0; c < 8; ++c) {
            const int tt = vA + c;           // slot index, valid < degd
            const float w = ((unsigned)tt < (unsigned)degd) ? pw[c] : 0.f;
            acc0[c].x += w * ba0.x; acc0[c].y += w * ba0.y;
            acc0[c].z += w * ba0.z; acc0[c].w += w * ba0.w;
            acc1[c].x += w * ba1.x; acc1[c].y += w * ba1.y;
            acc1[c].z += w * ba1.z; acc1[c].w += w * ba1.w;
        }
        ba0 = bn0; ba1 = bn1; vA = vN; dA = dN;
        #pragma unroll
        for (int c = 0; c < 8; ++c) pw[c] = pn[c];
    }

    // half-merge in registers, then cross-wave via LDS
    #pragma unroll
    for (int c = 0; c < 8; ++c) {
        acc0[c].x += __shfl_xor(acc0[c].x, 32); acc0[c].y += __shfl_xor(acc0[c].y, 32);
        acc0[c].z += __shfl_xor(acc0[c].z, 32); acc0[c].w += __shfl_xor(acc0[c].w, 32);
        acc1[c].x += __shfl_xor(acc1[c].x, 32); acc1[c].y += __shfl_xor(acc1[c].y, 32);
        acc1[c].z += __shfl_xor(acc1[c].z, 32); acc1[c].w += __shfl_xor(acc1[c].w, 32);
    }

    __shared__ float s_mrg[2 * 8 * ROW];   // merge[w][c][256], 16KB
    if (half == 0) {
        #pragma unroll
        for (int c = 0; c < 8; ++c) {
            *(float4*)(&s_mrg[(wid * 8 + c) * 256 + segf])     = acc0[c];
            *(float4*)(&s_mrg[(wid * 8 + c) * 256 + segf + 4]) = acc1[c];
        }
    }
    __syncthreads();

    float* vob = vo + b * bstr;
    #pragma unroll
    for (int q2 = 0; q2 < 4; ++q2) {
        const int c = 4 * wid + q2;
        const int src = (s0 + 7 * c) & (N_TOK - 1);
        float* vop = vob + (size_t)src * ROW + lane * 4;
        const float4 a0 = *(const float4*)(&s_mrg[(c)     * 256 + lane * 4]);
        const float4 a1 = *(const float4*)(&s_mrg[(8 + c) * 256 + lane * 4]);
        float4 o = *(const float4*)vop;
        o.x += a0.x + a1.x;
        o.y += a0.y + a1.y;
        o.z += a0.z + a1.z;
        o.w += a0.w + a1.w;
        *(float4*)vop = o;
    }
}

extern "C" void kernel_launch(void* const* d_in, const int* in_sizes, int n_in,
                              void* d_out, int out_size, void* d_ws, size_t ws_size,
                              hipStream_t stream) {
    const float* vf = (const float*)d_in[0];
    const float* vb = (const float*)d_in[1];
    const float* q  = (const float*)d_in[2];
    const float* k  = (const float*)d_in[3];

    float* vo = (float*)d_out;
    float* pT = (float*)d_ws;   // BS * PT_SZ floats (~12.5MB)

    fwd_kernel<<<dim3(1024), dim3(128), 0, stream>>>(vf, q, k, pT, vo);
    rev_kernel<<<dim3(1024), dim3(128), 0, stream>>>(vb, pT, vo);
}